// Round 3
// baseline (2523.888 us; speedup 1.0000x reference)
//
#include <hip/hip_runtime.h>
#include <hip/hip_bf16.h>

// GRU-GAN generator, MI355X. Round 12 — SINGLE barrier per step.
// B=512, H=64, S=2048, F=32. 32 blocks x 512 threads (8 waves, 2/SIMD).
// Every wave is a gate wave (dir=w>>2, cb=w&3); waves 0,1 also do out-proj.
//
// The R12 idea: remove the x-handoff barrier entirely. Each gate wave
// redundantly computes the FULL latent x(t+1) in-register from h(t+1),
// using row-permuted Wlat tiles so the MFMA D-layout (col=lane&15,
// row=4*quad+reg) lands exactly in B-fragment layout (n=lane&15,
// k=8*quad+i) for the next step's gi MFMAs:
//   tile A rows 8q+r, tile B rows 8q+4+r, tiles C/D same +32.
// Step = [gi MFMA + merged-rcp elementwise + h-frag LDS write]
//        -> bar_lgkm (the ONLY barrier)
//        -> [4x ds_read_b128 h(t+1) -> 16 latent MFMA -> xa regs; 6 gh MFMA;
//            waves 0,1: lk2+pack, 2 out MFMA, sigmoid, un-drained store y(t)].
// Chain per step crosses ONE barrier + ONE LDS round-trip (was 2+2).
// Numerics: identical fragment values and MFMA association order as R10/R11
// (latent 2+2 split, lk2 on f32 before pack) -> absmax unchanged.

#define NBATCH 512
#define NH 64
#define NS 2048
#define NF 32
#define MROW 16

typedef short s16x8 __attribute__((ext_vector_type(8)));
typedef float f32x4 __attribute__((ext_vector_type(4)));

#define MFMA(a, b, c) __builtin_amdgcn_mfma_f32_16x16x32_bf16((a), (b), (c), 0, 0, 0)

#define NLOG2E  (-1.4426950408889634f)   // -log2(e)
#define N2LOG2E (-2.8853900817779268f)   // -2*log2(e)

__device__ __forceinline__ void bar_lgkm() {
    // LDS-visibility barrier: drain lgkm only, vmcnt (y-stores) stays in flight
    asm volatile("s_waitcnt lgkmcnt(0)\n\ts_barrier" ::: "memory");
}

__device__ __forceinline__ short f2bf(float f) {
    return (short)((__float_as_uint(f) + 0x8000u) >> 16);
}

__device__ __forceinline__ f32x4 v_exp2(f32x4 a) {
    f32x4 r;
#pragma unroll
    for (int i = 0; i < 4; ++i) r[i] = __builtin_amdgcn_exp2f(a[i]);
    return r;
}

__device__ __forceinline__ f32x4 v_rcp(f32x4 a) {
    f32x4 r;
#pragma unroll
    for (int i = 0; i < 4; ++i) r[i] = __builtin_amdgcn_rcpf(a[i]);
    return r;
}

__device__ __forceinline__ f32x4 v_lk(f32x4 a) {
    f32x4 b = a * 0.01f;
    f32x4 r;
#pragma unroll
    for (int i = 0; i < 4; ++i) r[i] = fmaxf(a[i], b[i]);
    return r;
}

__device__ __forceinline__ f32x4 v_sigm(f32x4 a) {
    return v_rcp(v_exp2(a * NLOG2E) + 1.0f);
}

__device__ __forceinline__ int2 pk4bf(f32x4 v) {
    union { __hip_bfloat162 b; int i; } lo, hi;
    float2 a; a.x = v[0]; a.y = v[1];
    float2 b; b.x = v[2]; b.y = v[3];
    lo.b = __float22bfloat162_rn(a);
    hi.b = __float22bfloat162_rn(b);
    int2 r; r.x = lo.i; r.y = hi.i;
    return r;
}

__device__ __forceinline__ s16x8 pack2(int2 a, int2 b) {
    union { struct { int2 a, b; } p; s16x8 s; } u;
    u.p.a = a; u.p.b = b;
    return u.s;
}

__device__ __forceinline__ s16x8 bfragW(const float* __restrict__ W, int ldk,
                                        int row, int kf, int quad) {
    const float* p = W + (size_t)row * ldk + kf * 32 + quad * 8;
    s16x8 r;
#pragma unroll
    for (int i = 0; i < 8; ++i) r[i] = f2bf(p[i]);
    return r;
}

__device__ __forceinline__ f32x4 bias4(const float* __restrict__ p) {
    const float4 v = *(const float4*)p;
    f32x4 r = {v.x, v.y, v.z, v.w};
    return r;
}

__global__ __launch_bounds__(512)
void grugan_kernel(const float* __restrict__ noise,
                   const float* __restrict__ Wihf, const float* __restrict__ Whhf,
                   const float* __restrict__ bihf, const float* __restrict__ bhhf,
                   const float* __restrict__ Wihb, const float* __restrict__ Whhb,
                   const float* __restrict__ bihb, const float* __restrict__ bhhb,
                   const float* __restrict__ Wlat, const float* __restrict__ blat,
                   const float* __restrict__ Wout, const float* __restrict__ bout,
                   float* __restrict__ out)
{
    // h double buffer, fragment-linear: [buf][dir][frag][quad][n][8] shorts.
    // Read (B-frag): addr = base + lane*16 -> conflict-free by construction.
    __shared__ __align__(16) short Hs[2][2][2][4][16][8];

    const int tid  = threadIdx.x;
    const int wave = tid >> 6;
    const int lane = tid & 63;
    const int n    = lane & 15;   // batch row within tile
    const int quad = lane >> 4;
    const int row0 = blockIdx.x * MROW;

    const int dir = wave >> 2;    // 0=fwd, 1=bwd
    const int cb  = wave & 3;     // j-chunk of 16 gate columns
    const int jq  = cb * 16 + quad * 4;
    // h write-slot for a 4-col int2 at col0 = cb*16 + quad*4:
    const int wfrag = cb >> 1;
    const int wq    = ((cb & 1) << 1) | (quad >> 1);
    const int we    = (quad & 1) << 2;

    // ---------------- weight fragments (one-time) ----------------
    const int jrow = cb * 16 + n;
    const float* Wih = dir ? Wihb : Wihf;
    const float* Whh = dir ? Whhb : Whhf;
    const float* bih = dir ? bihb : bihf;
    const float* bhh = dir ? bhhb : bhhf;

    s16x8 wir0 = bfragW(Wih, NH,   0 + jrow, 0, quad);
    s16x8 wir1 = bfragW(Wih, NH,   0 + jrow, 1, quad);
    s16x8 wiz0 = bfragW(Wih, NH,  64 + jrow, 0, quad);
    s16x8 wiz1 = bfragW(Wih, NH,  64 + jrow, 1, quad);
    s16x8 win0 = bfragW(Wih, NH, 128 + jrow, 0, quad);
    s16x8 win1 = bfragW(Wih, NH, 128 + jrow, 1, quad);
    s16x8 whr0 = bfragW(Whh, NH,   0 + jrow, 0, quad);
    s16x8 whr1 = bfragW(Whh, NH,   0 + jrow, 1, quad);
    s16x8 whz0 = bfragW(Whh, NH,  64 + jrow, 0, quad);
    s16x8 whz1 = bfragW(Whh, NH,  64 + jrow, 1, quad);
    s16x8 whn0 = bfragW(Whh, NH, 128 + jrow, 0, quad);
    s16x8 whn1 = bfragW(Whh, NH, 128 + jrow, 1, quad);

    f32x4 initR, initZ;
    {
        f32x4 a = bias4(&bih[jq]),      b = bias4(&bhh[jq]);
        initR = a + b;
        f32x4 c = bias4(&bih[64 + jq]), d = bias4(&bhh[64 + jq]);
        initZ = c + d;
    }
    const f32x4 initN1 = bias4(&bih[128 + jq]);
    const f32x4 initN2 = bias4(&bhh[128 + jq]);

    // latent weights, ROW-PERMUTED tiles so D-layout == next B-frag layout:
    //   tile A: Wlat row 8*(n>>2)+(n&3);  B: +4;  C: +32;  D: +36.
    const int prow = 8 * (n >> 2) + (n & 3);
    s16x8 wlA0 = bfragW(Wlat, 2 * NH, prow,      0, quad);
    s16x8 wlA1 = bfragW(Wlat, 2 * NH, prow,      1, quad);
    s16x8 wlA2 = bfragW(Wlat, 2 * NH, prow,      2, quad);
    s16x8 wlA3 = bfragW(Wlat, 2 * NH, prow,      3, quad);
    s16x8 wlB0 = bfragW(Wlat, 2 * NH, prow + 4,  0, quad);
    s16x8 wlB1 = bfragW(Wlat, 2 * NH, prow + 4,  1, quad);
    s16x8 wlB2 = bfragW(Wlat, 2 * NH, prow + 4,  2, quad);
    s16x8 wlB3 = bfragW(Wlat, 2 * NH, prow + 4,  3, quad);
    s16x8 wlC0 = bfragW(Wlat, 2 * NH, prow + 32, 0, quad);
    s16x8 wlC1 = bfragW(Wlat, 2 * NH, prow + 32, 1, quad);
    s16x8 wlC2 = bfragW(Wlat, 2 * NH, prow + 32, 2, quad);
    s16x8 wlC3 = bfragW(Wlat, 2 * NH, prow + 32, 3, quad);
    s16x8 wlD0 = bfragW(Wlat, 2 * NH, prow + 36, 0, quad);
    s16x8 wlD1 = bfragW(Wlat, 2 * NH, prow + 36, 1, quad);
    s16x8 wlD2 = bfragW(Wlat, 2 * NH, prow + 36, 2, quad);
    s16x8 wlD3 = bfragW(Wlat, 2 * NH, prow + 36, 3, quad);
    const f32x4 initXA = bias4(&blat[ 0 + 8 * quad]);
    const f32x4 initXB = bias4(&blat[ 4 + 8 * quad]);
    const f32x4 initXC = bias4(&blat[32 + 8 * quad]);
    const f32x4 initXD = bias4(&blat[36 + 8 * quad]);

    // out-proj state (waves 0,1 only; f-tile f0 = wave*16)
    s16x8 wo0 = {};
    s16x8 wo1 = {};
    f32x4 initO = {0.f, 0.f, 0.f, 0.f};
    float* orow = nullptr;
    if (wave < 2) {
        const int f0 = wave * 16;
        wo0   = bfragW(Wout, NH, f0 + n, 0, quad);
        wo1   = bfragW(Wout, NH, f0 + n, 1, quad);
        initO = bias4(&bout[f0 + quad * 4]);
        orow  = out + (size_t)(row0 + n) * (NS * NF) + f0 + quad * 4;
    }
    const f32x4 zero4 = {0.f, 0.f, 0.f, 0.f};

    // ---------------- prologue: h(0) ----------------
    f32x4 hreg;
    {
        const float4 nz = *(const float4*)&noise[(size_t)(row0 + n) * NH + jq];
        hreg[0] = nz.x; hreg[1] = nz.y; hreg[2] = nz.z; hreg[3] = nz.w;
        *(int2*)&Hs[0][dir][wfrag][wq][n][we] = pk4bf(hreg);
    }
    __syncthreads();

    f32x4 accR, accZ, accN2;
    {
        s16x8 h00 = *(const s16x8*)&Hs[0][dir][0][quad][n][0];
        s16x8 h01 = *(const s16x8*)&Hs[0][dir][1][quad][n][0];
        accR  = MFMA(whr0, h00, initR);  accR  = MFMA(whr1, h01, accR);
        accZ  = MFMA(whz0, h00, initZ);  accZ  = MFMA(whz1, h01, accZ);
        accN2 = MFMA(whn0, h00, initN2); accN2 = MFMA(whn1, h01, accN2);
    }
    s16x8 xa0 = {};   // x(0) = 0
    s16x8 xa1 = {};

    // ---------------- main loop: one barrier per step ----------------
    // PB = (T+1)&1 = buffer holding h(T+1).
#define STEP(PB, T) do {                                                        \
        /* pre-barrier: gi MFMA + merged-rcp elementwise + h-frag write */      \
        accR = MFMA(wir0, xa0, accR);   accR = MFMA(wir1, xa1, accR);           \
        accZ = MFMA(wiz0, xa0, accZ);   accZ = MFMA(wiz1, xa1, accZ);           \
        f32x4 accN1 = MFMA(win0, xa0, initN1);                                  \
        accN1 = MFMA(win1, xa1, accN1);                                         \
        f32x4 eR = v_exp2(accR * NLOG2E);                                       \
        f32x4 rr = v_rcp(eR + 1.0f);                                            \
        f32x4 u  = accN1 + rr * accN2;                                          \
        f32x4 eU = v_exp2(u * N2LOG2E);                                         \
        f32x4 eZ = v_exp2(accZ * NLOG2E);                                       \
        f32x4 numer = (eZ + hreg) + eU * (hreg - eZ);                           \
        f32x4 denom = (eU + 1.0f) * (eZ + 1.0f);                                \
        hreg = numer * v_rcp(denom);                                            \
        *(int2*)&Hs[PB][dir][wfrag][wq][n][we] = pk4bf(hreg);                   \
        bar_lgkm();   /* THE barrier: h(T+1) visible */                         \
        /* post-barrier: read full h(T+1), latent -> xa regs, gh acc */         \
        s16x8 hf0 = *(const s16x8*)&Hs[PB][0][0][quad][n][0];                   \
        s16x8 hf1 = *(const s16x8*)&Hs[PB][0][1][quad][n][0];                   \
        s16x8 hb0 = *(const s16x8*)&Hs[PB][1][0][quad][n][0];                   \
        s16x8 hb1 = *(const s16x8*)&Hs[PB][1][1][quad][n][0];                   \
        f32x4 la, lb, lc, ld;                                                   \
        {                                                                       \
            f32x4 pA = MFMA(wlA0, hf0, initXA); pA = MFMA(wlA1, hf1, pA);       \
            f32x4 qA = MFMA(wlA2, hb0, zero4);  qA = MFMA(wlA3, hb1, qA);       \
            la = pA + qA;                                                       \
            f32x4 pB = MFMA(wlB0, hf0, initXB); pB = MFMA(wlB1, hf1, pB);       \
            f32x4 qB = MFMA(wlB2, hb0, zero4);  qB = MFMA(wlB3, hb1, qB);       \
            lb = pB + qB;                                                       \
            f32x4 pC = MFMA(wlC0, hf0, initXC); pC = MFMA(wlC1, hf1, pC);       \
            f32x4 qC = MFMA(wlC2, hb0, zero4);  qC = MFMA(wlC3, hb1, qC);       \
            lc = pC + qC;                                                       \
            f32x4 pD = MFMA(wlD0, hf0, initXD); pD = MFMA(wlD1, hf1, pD);       \
            f32x4 qD = MFMA(wlD2, hb0, zero4);  qD = MFMA(wlD3, hb1, qD);       \
            ld = pD + qD;                                                       \
        }                                                                       \
        f32x4 xA = v_lk(la), xB = v_lk(lb), xC = v_lk(lc), xD = v_lk(ld);       \
        xa0 = pack2(pk4bf(xA), pk4bf(xB));                                      \
        xa1 = pack2(pk4bf(xC), pk4bf(xD));                                      \
        {                                                                       \
            s16x8 ha0 = dir ? hb0 : hf0;                                        \
            s16x8 ha1 = dir ? hb1 : hf1;                                        \
            accR  = MFMA(whr0, ha0, initR);  accR  = MFMA(whr1, ha1, accR);     \
            accZ  = MFMA(whz0, ha0, initZ);  accZ  = MFMA(whz1, ha1, accZ);     \
            accN2 = MFMA(whn0, ha0, initN2); accN2 = MFMA(whn1, ha1, accN2);    \
        }                                                                       \
        if (wave < 2) {                                                         \
            /* out-proj: y(T) = sigm(Wout . lk(x(T+1)) + bout); store stays */  \
            /* un-drained forever (bar_lgkm never waits vmcnt). */              \
            s16x8 xo0 = pack2(pk4bf(v_lk(xA)), pk4bf(v_lk(xB)));                \
            s16x8 xo1 = pack2(pk4bf(v_lk(xC)), pk4bf(v_lk(xD)));                \
            f32x4 po = MFMA(wo0, xo0, initO);                                   \
            po = MFMA(wo1, xo1, po);                                            \
            *(f32x4*)(orow + (size_t)(T) * NF) = v_sigm(po);                    \
        }                                                                       \
    } while (0)

    for (int t = 0; t < NS; t += 2) {
        STEP(1, t);
        STEP(0, t + 1);
    }
#undef STEP
}

extern "C" void kernel_launch(void* const* d_in, const int* in_sizes, int n_in,
                              void* d_out, int out_size, void* d_ws, size_t ws_size,
                              hipStream_t stream) {
    const float* noise = (const float*)d_in[0];
    const float* Wihf  = (const float*)d_in[1];
    const float* Whhf  = (const float*)d_in[2];
    const float* bihf  = (const float*)d_in[3];
    const float* bhhf  = (const float*)d_in[4];
    const float* Wihb  = (const float*)d_in[5];
    const float* Whhb  = (const float*)d_in[6];
    const float* bihb  = (const float*)d_in[7];
    const float* bhhb  = (const float*)d_in[8];
    const float* Wlat  = (const float*)d_in[9];
    const float* blat  = (const float*)d_in[10];
    const float* Wout  = (const float*)d_in[11];
    const float* bout  = (const float*)d_in[12];

    grugan_kernel<<<dim3(NBATCH / MROW), dim3(512), 0, stream>>>(
        noise, Wihf, Whhf, bihf, bhhf, Wihb, Whhb, bihb, bhhb,
        Wlat, blat, Wout, bout, (float*)d_out);
}

// Round 4
// 1581.096 us; speedup vs baseline: 1.5963x; 1.5963x over previous
//
#include <hip/hip_runtime.h>
#include <hip/hip_bf16.h>

// GRU-GAN generator, MI355X. Round 13 — R10 base (best: 1512us) + per-leg
// s_setprio wave-role arbitration. R12 (single-barrier, redundant latent)
// regressed 2419us: VGPR 128, issue-burst on chain; reverted.
// B=512, H=64, S=2048, F=32. 32 blocks x 768 threads (12 waves, 3/SIMD).
// Block = 16 batch rows (one M=16 MFMA tile, transposed D[j][m] layout).
//   waves 0-7 : gates (dir=w>>2, cb=w&3). Leg1 (b2->b1): x-read, 6 gi MFMA,
//               merged-rcp GRU elementwise, packed h write  [PRIO 1 — leg1
//               straggler]. Leg2: 6 gh MFMA (carried regs)  [prio 0].
//   waves 8-11: latent (+ out-proj on waves 8-9). Leg1 (waves 8-9): X2s read,
//               2 MFMA, sigmoid, un-drained f32x4 store      [prio 0 — slack].
//               Leg2: h(t+1) read (both dirs), 2+2 MFMA, leaky, Xs/X2s writes
//               [PRIO 1 — leg2 straggler].
// Rationale: active-CU VALUBusy ~50% (whole-chip 6.3% x 256/32) => critical
// wave's chain is diluted by co-resident waves' issue during post-barrier
// bursts; setprio lets each leg's straggler win issue arbitration.
// Barriers: gates plain __syncthreads (their vmcnt is always 0); latent path
// raw s_barrier / lgkm-only drain so y-stores never block.
// Numerics: exact merged-rcp GRU update, bf16 state via v_cvt_pk_bf16_f32
// (identical to R10 -> absmax 0.00390625).

#define NBATCH 512
#define NH 64
#define NS 2048
#define NF 32
#define MROW 16
#define LDH 72    // padded LDS row stride (shorts): 144 B

typedef short s16x8 __attribute__((ext_vector_type(8)));
typedef float f32x4 __attribute__((ext_vector_type(4)));

#define MFMA(a, b, c) __builtin_amdgcn_mfma_f32_16x16x32_bf16((a), (b), (c), 0, 0, 0)

#define NLOG2E  (-1.4426950408889634f)   // -log2(e)
#define N2LOG2E (-2.8853900817779268f)   // -2*log2(e)

__device__ __forceinline__ void bar_nodrain() {
    // raw barrier: no vmcnt/lgkmcnt drain -> global stores stay in flight
    asm volatile("s_barrier" ::: "memory");
}

__device__ __forceinline__ void bar_lgkm() {
    // LDS-visibility barrier: drain lgkm only, vmcnt left outstanding
    asm volatile("s_waitcnt lgkmcnt(0)\n\ts_barrier" ::: "memory");
}

__device__ __forceinline__ short f2bf(float f) {
    return (short)((__float_as_uint(f) + 0x8000u) >> 16);
}

__device__ __forceinline__ f32x4 v_exp2(f32x4 a) {
    f32x4 r;
#pragma unroll
    for (int i = 0; i < 4; ++i) r[i] = __builtin_amdgcn_exp2f(a[i]);
    return r;
}

__device__ __forceinline__ f32x4 v_rcp(f32x4 a) {
    f32x4 r;
#pragma unroll
    for (int i = 0; i < 4; ++i) r[i] = __builtin_amdgcn_rcpf(a[i]);
    return r;
}

__device__ __forceinline__ f32x4 v_lk(f32x4 a) {
    f32x4 b = a * 0.01f;
    f32x4 r;
#pragma unroll
    for (int i = 0; i < 4; ++i) r[i] = fmaxf(a[i], b[i]);
    return r;
}

__device__ __forceinline__ f32x4 v_sigm(f32x4 a) {
    return v_rcp(v_exp2(a * NLOG2E) + 1.0f);
}

__device__ __forceinline__ int2 pk4bf(f32x4 v) {
    union { __hip_bfloat162 b; int i; } lo, hi;
    float2 a; a.x = v[0]; a.y = v[1];
    float2 b; b.x = v[2]; b.y = v[3];
    lo.b = __float22bfloat162_rn(a);
    hi.b = __float22bfloat162_rn(b);
    int2 r; r.x = lo.i; r.y = hi.i;
    return r;
}

__device__ __forceinline__ s16x8 bfragW(const float* __restrict__ W, int ldk,
                                        int row, int kf, int quad) {
    const float* p = W + (size_t)row * ldk + kf * 32 + quad * 8;
    s16x8 r;
#pragma unroll
    for (int i = 0; i < 8; ++i) r[i] = f2bf(p[i]);
    return r;
}

__device__ __forceinline__ f32x4 bias4(const float* __restrict__ p) {
    const float4 v = *(const float4*)p;
    f32x4 r = {v.x, v.y, v.z, v.w};
    return r;
}

__global__ __launch_bounds__(768)
void grugan_kernel(const float* __restrict__ noise,
                   const float* __restrict__ Wihf, const float* __restrict__ Whhf,
                   const float* __restrict__ bihf, const float* __restrict__ bhhf,
                   const float* __restrict__ Wihb, const float* __restrict__ Whhb,
                   const float* __restrict__ bihb, const float* __restrict__ bhhb,
                   const float* __restrict__ Wlat, const float* __restrict__ blat,
                   const float* __restrict__ Wout, const float* __restrict__ bout,
                   float* __restrict__ out)
{
    __shared__ __align__(16) short Xs[2][MROW][LDH];
    __shared__ __align__(16) short X2s[2][MROW][LDH];
    __shared__ __align__(16) short Hs[2][2][MROW][LDH];

    const int tid  = threadIdx.x;
    const int wave = tid >> 6;
    const int lane = tid & 63;
    const int n    = lane & 15;   // batch row within tile
    const int quad = lane >> 4;
    const int row0 = blockIdx.x * MROW;

    // zero x(0); init h(0) (gate waves hold hreg; both dirs covered)
    for (int idx = tid; idx < MROW * LDH; idx += 768) (&Xs[0][0][0])[idx] = 0;
    f32x4 hreg = {0.f, 0.f, 0.f, 0.f};
    const int gdir = wave >> 2;             // valid for waves 0-7
    const int gjq  = (wave & 3) * 16 + quad * 4;
    if (wave < 8) {
        const float4 nz = *(const float4*)&noise[(size_t)(row0 + n) * NH + gjq];
        hreg[0] = nz.x; hreg[1] = nz.y; hreg[2] = nz.z; hreg[3] = nz.w;
        *(int2*)&Hs[0][gdir][n][gjq] = pk4bf(hreg);
    }
    __syncthreads();

    if (wave < 8) {
        // ======================= GATE WAVES =======================
        const int dir  = gdir;
        const int cb   = wave & 3;
        const int jrow = cb * 16 + n;
        const int jq   = gjq;
        const float* Wih = dir ? Wihb : Wihf;
        const float* Whh = dir ? Whhb : Whhf;
        const float* bih = dir ? bihb : bihf;
        const float* bhh = dir ? bhhb : bhhf;

        s16x8 wir0 = bfragW(Wih, NH,   0 + jrow, 0, quad);
        s16x8 wir1 = bfragW(Wih, NH,   0 + jrow, 1, quad);
        s16x8 wiz0 = bfragW(Wih, NH,  64 + jrow, 0, quad);
        s16x8 wiz1 = bfragW(Wih, NH,  64 + jrow, 1, quad);
        s16x8 win0 = bfragW(Wih, NH, 128 + jrow, 0, quad);
        s16x8 win1 = bfragW(Wih, NH, 128 + jrow, 1, quad);
        s16x8 whr0 = bfragW(Whh, NH,   0 + jrow, 0, quad);
        s16x8 whr1 = bfragW(Whh, NH,   0 + jrow, 1, quad);
        s16x8 whz0 = bfragW(Whh, NH,  64 + jrow, 0, quad);
        s16x8 whz1 = bfragW(Whh, NH,  64 + jrow, 1, quad);
        s16x8 whn0 = bfragW(Whh, NH, 128 + jrow, 0, quad);
        s16x8 whn1 = bfragW(Whh, NH, 128 + jrow, 1, quad);
        f32x4 initR, initZ;
        {
            f32x4 a = bias4(&bih[jq]),      b = bias4(&bhh[jq]);
            initR = a + b;
            f32x4 c = bias4(&bih[64 + jq]), d = bias4(&bhh[64 + jq]);
            initZ = c + d;
        }
        const f32x4 initN1 = bias4(&bih[128 + jq]);
        const f32x4 initN2 = bias4(&bhh[128 + jq]);

        // prologue: gh accumulators for t=0 from h(0)
        f32x4 accR, accZ, accN2;
        {
            s16x8 ha0 = *(const s16x8*)&Hs[0][dir][n][quad * 8];
            s16x8 ha1 = *(const s16x8*)&Hs[0][dir][n][32 + quad * 8];
            accR  = MFMA(whr0, ha0, initR);  accR  = MFMA(whr1, ha1, accR);
            accZ  = MFMA(whz0, ha0, initZ);  accZ  = MFMA(whz1, ha1, accZ);
            accN2 = MFMA(whn0, ha0, initN2); accN2 = MFMA(whn1, ha1, accN2);
        }

#define GSTEP(HB) do {                                                          \
        __builtin_amdgcn_s_setprio(1);  /* leg1: gates are the straggler */     \
        s16x8 xa0 = *(const s16x8*)&Xs[HB][n][quad * 8];                        \
        s16x8 xa1 = *(const s16x8*)&Xs[HB][n][32 + quad * 8];                   \
        accR = MFMA(wir0, xa0, accR);   accR = MFMA(wir1, xa1, accR);           \
        accZ = MFMA(wiz0, xa0, accZ);   accZ = MFMA(wiz1, xa1, accZ);           \
        f32x4 accN1 = MFMA(win0, xa0, initN1);                                  \
        accN1 = MFMA(win1, xa1, accN1);                                         \
        f32x4 eR = v_exp2(accR * NLOG2E);                                       \
        f32x4 rr = v_rcp(eR + 1.0f);                                            \
        f32x4 u  = accN1 + rr * accN2;                                          \
        f32x4 eU = v_exp2(u * N2LOG2E);                                         \
        f32x4 eZ = v_exp2(accZ * NLOG2E);                                       \
        f32x4 numer = (eZ + hreg) + eU * (hreg - eZ);                           \
        f32x4 denom = (eU + 1.0f) * (eZ + 1.0f);                                \
        hreg = numer * v_rcp(denom);                                            \
        *(int2*)&Hs[(HB) ^ 1][dir][n][jq] = pk4bf(hreg);                        \
        __builtin_amdgcn_s_setprio(0);  /* leg2: yield to latent waves */       \
        __syncthreads();  /* b1: H(t+1) visible */                              \
        {                                                                       \
            s16x8 ha0 = *(const s16x8*)&Hs[(HB) ^ 1][dir][n][quad * 8];         \
            s16x8 ha1 = *(const s16x8*)&Hs[(HB) ^ 1][dir][n][32 + quad * 8];    \
            accR  = MFMA(whr0, ha0, initR);  accR  = MFMA(whr1, ha1, accR);     \
            accZ  = MFMA(whz0, ha0, initZ);  accZ  = MFMA(whz1, ha1, accZ);     \
            accN2 = MFMA(whn0, ha0, initN2); accN2 = MFMA(whn1, ha1, accN2);    \
        }                                                                       \
        __syncthreads();  /* b2: x(t+1) visible */                              \
    } while (0)

        for (int t = 0; t < NS; t += 2) {
            GSTEP(0);
            GSTEP(1);
        }
#undef GSTEP
    } else {
        // =============== LATENT WAVES (+ fused OUT-PROJ on lt<2) ===============
        const int lt = wave & 3;
        const int nq = lt * 16 + quad * 4;
        s16x8 wl0 = bfragW(Wlat, 2 * NH, lt * 16 + n, 0, quad);
        s16x8 wl1 = bfragW(Wlat, 2 * NH, lt * 16 + n, 1, quad);
        s16x8 wl2 = bfragW(Wlat, 2 * NH, lt * 16 + n, 2, quad);
        s16x8 wl3 = bfragW(Wlat, 2 * NH, lt * 16 + n, 3, quad);
        const f32x4 initL = bias4(&blat[lt * 16 + quad * 4]);

        // out-proj state (waves 8-9 only: f-tile f0 = lt*16)
        s16x8 wo0 = {};
        s16x8 wo1 = {};
        f32x4 initO = {0.f, 0.f, 0.f, 0.f};
        float* orow = nullptr;
        if (lt < 2) {
            const int f0 = lt * 16;
            wo0   = bfragW(Wout, NH, f0 + n, 0, quad);
            wo1   = bfragW(Wout, NH, f0 + n, 1, quad);
            initO = bias4(&bout[f0 + quad * 4]);
            orow  = out + (size_t)(row0 + n) * (NS * NF) + f0 + quad * 4;
        }
        const f32x4 zero4 = {0.f, 0.f, 0.f, 0.f};

#define LOSTEP(HB, T) do {                                                      \
        if (lt < 2 && (T) > 0) {                                                \
            /* leg1 (prio 0 — slack): out-proj of y(T-1) from X2s[HB];  */      \
            /* store never drained (raw barriers keep vmcnt outstanding). */    \
            s16x8 p0 = *(const s16x8*)&X2s[HB][n][quad * 8];                    \
            s16x8 p1 = *(const s16x8*)&X2s[HB][n][32 + quad * 8];               \
            f32x4 po = MFMA(wo0, p0, initO);                                    \
            po = MFMA(wo1, p1, po);                                             \
            *(f32x4*)(orow + (size_t)((T) - 1) * NF) = v_sigm(po);              \
        }                                                                       \
        bar_nodrain();    /* b1: H(T+1) visible (we have nothing pending) */    \
        __builtin_amdgcn_s_setprio(1);  /* leg2: latent is the straggler */     \
        s16x8 fa0 = *(const s16x8*)&Hs[(HB) ^ 1][0][n][quad * 8];               \
        s16x8 fa1 = *(const s16x8*)&Hs[(HB) ^ 1][0][n][32 + quad * 8];          \
        s16x8 ba0 = *(const s16x8*)&Hs[(HB) ^ 1][1][n][quad * 8];               \
        s16x8 ba1 = *(const s16x8*)&Hs[(HB) ^ 1][1][n][32 + quad * 8];          \
        f32x4 lac1 = MFMA(wl0, fa0, initL);                                     \
        lac1 = MFMA(wl1, fa1, lac1);                                            \
        f32x4 lac2 = MFMA(wl2, ba0, zero4);                                     \
        lac2 = MFMA(wl3, ba1, lac2);                                            \
        f32x4 la = v_lk(lac1 + lac2);                                           \
        *(int2*)&Xs[(HB) ^ 1][n][nq]  = pk4bf(la);                              \
        *(int2*)&X2s[(HB) ^ 1][n][nq] = pk4bf(v_lk(la));                        \
        __builtin_amdgcn_s_setprio(0);  /* leg1: yield to gate waves */         \
        bar_lgkm();       /* b2: x(T+1) visible (lgkm drain only) */            \
    } while (0)

        for (int t = 0; t < NS; t += 2) {
            LOSTEP(0, t);
            LOSTEP(1, t + 1);
        }
#undef LOSTEP

        // epilogue: y(NS-1) from X2s[0] (= lk2(x(NS)), written at T=NS-1,
        // visible via the loop's final bar_lgkm)
        if (lt < 2) {
            s16x8 p0 = *(const s16x8*)&X2s[0][n][quad * 8];
            s16x8 p1 = *(const s16x8*)&X2s[0][n][32 + quad * 8];
            f32x4 po = MFMA(wo0, p0, initO);
            po = MFMA(wo1, p1, po);
            *(f32x4*)(orow + (size_t)(NS - 1) * NF) = v_sigm(po);
        }
    }
}

extern "C" void kernel_launch(void* const* d_in, const int* in_sizes, int n_in,
                              void* d_out, int out_size, void* d_ws, size_t ws_size,
                              hipStream_t stream) {
    const float* noise = (const float*)d_in[0];
    const float* Wihf  = (const float*)d_in[1];
    const float* Whhf  = (const float*)d_in[2];
    const float* bihf  = (const float*)d_in[3];
    const float* bhhf  = (const float*)d_in[4];
    const float* Wihb  = (const float*)d_in[5];
    const float* Whhb  = (const float*)d_in[6];
    const float* bihb  = (const float*)d_in[7];
    const float* bhhb  = (const float*)d_in[8];
    const float* Wlat  = (const float*)d_in[9];
    const float* blat  = (const float*)d_in[10];
    const float* Wout  = (const float*)d_in[11];
    const float* bout  = (const float*)d_in[12];

    grugan_kernel<<<dim3(NBATCH / MROW), dim3(768), 0, stream>>>(
        noise, Wihf, Whhf, bihf, bhhf, Wihb, Whhb, bihb, bhhb,
        Wlat, blat, Wout, bout, (float*)d_out);
}

// Round 5
// 1506.077 us; speedup vs baseline: 1.6758x; 1.0498x over previous
//
#include <hip/hip_runtime.h>
#include <hip/hip_bf16.h>

// GRU-GAN generator, MI355X. Round 14 — R13 base (1459us) + log2e scale
// folding into bf16 weight conversion (issue-bound shave on active CUs).
// Active-CU model (counters are 8x diluted: 32/256 CUs): VALU ~52% busy,
// MFMA ~27% -> ~half issue-bound, half barrier bubbles. This round removes
// VALU ops from the gate critical leg:
//   - Wir/Whr/bR scaled by -log2e  -> eR = exp2(accR) directly
//   - Wiz/Whz/bZ scaled by -log2e  -> eZ = exp2(accZ)
//   - Win/Whn/bN scaled by -2log2e -> eU = exp2(accN1 + rr*accN2)
//   - Wout/bout scaled by -log2e   -> sigm = rcp(exp2(po)+1)
//   - X2s = lk(lk(x)) == max(x, 1e-4*x): computed straight from la
//     (parallel with Xs pack, breaks a dependent lk stage)
// Everything else (12 waves, roles, setprio, barriers) identical to R13.
// B=512, H=64, S=2048, F=32. 32 blocks x 768 threads (12 waves, 3/SIMD).

#define NBATCH 512
#define NH 64
#define NS 2048
#define NF 32
#define MROW 16
#define LDH 72    // padded LDS row stride (shorts): 144 B

typedef short s16x8 __attribute__((ext_vector_type(8)));
typedef float f32x4 __attribute__((ext_vector_type(4)));

#define MFMA(a, b, c) __builtin_amdgcn_mfma_f32_16x16x32_bf16((a), (b), (c), 0, 0, 0)

#define NLOG2E  (-1.4426950408889634f)   // -log2(e)
#define N2LOG2E (-2.8853900817779268f)   // -2*log2(e)

__device__ __forceinline__ void bar_nodrain() {
    asm volatile("s_barrier" ::: "memory");
}

__device__ __forceinline__ void bar_lgkm() {
    asm volatile("s_waitcnt lgkmcnt(0)\n\ts_barrier" ::: "memory");
}

__device__ __forceinline__ short f2bf(float f) {
    return (short)((__float_as_uint(f) + 0x8000u) >> 16);
}

__device__ __forceinline__ f32x4 v_exp2(f32x4 a) {
    f32x4 r;
#pragma unroll
    for (int i = 0; i < 4; ++i) r[i] = __builtin_amdgcn_exp2f(a[i]);
    return r;
}

__device__ __forceinline__ f32x4 v_rcp(f32x4 a) {
    f32x4 r;
#pragma unroll
    for (int i = 0; i < 4; ++i) r[i] = __builtin_amdgcn_rcpf(a[i]);
    return r;
}

__device__ __forceinline__ f32x4 v_lk(f32x4 a) {
    f32x4 b = a * 0.01f;
    f32x4 r;
#pragma unroll
    for (int i = 0; i < 4; ++i) r[i] = fmaxf(a[i], b[i]);
    return r;
}

// lk(lk(x)) = max(x, 1e-4*x) in one stage (x>=0 -> x; x<0 -> 1e-4*x)
__device__ __forceinline__ f32x4 v_lk2(f32x4 a) {
    f32x4 b = a * 1e-4f;
    f32x4 r;
#pragma unroll
    for (int i = 0; i < 4; ++i) r[i] = fmaxf(a[i], b[i]);
    return r;
}

// sigmoid of pre-scaled input: a = -log2e * z  ->  1/(1+2^a)
__device__ __forceinline__ f32x4 v_sigm_pre(f32x4 a) {
    return v_rcp(v_exp2(a) + 1.0f);
}

__device__ __forceinline__ int2 pk4bf(f32x4 v) {
    union { __hip_bfloat162 b; int i; } lo, hi;
    float2 a; a.x = v[0]; a.y = v[1];
    float2 b; b.x = v[2]; b.y = v[3];
    lo.b = __float22bfloat162_rn(a);
    hi.b = __float22bfloat162_rn(b);
    int2 r; r.x = lo.i; r.y = hi.i;
    return r;
}

__device__ __forceinline__ s16x8 bfragW(const float* __restrict__ W, int ldk,
                                        int row, int kf, int quad, float scale) {
    const float* p = W + (size_t)row * ldk + kf * 32 + quad * 8;
    s16x8 r;
#pragma unroll
    for (int i = 0; i < 8; ++i) r[i] = f2bf(p[i] * scale);
    return r;
}

__device__ __forceinline__ f32x4 bias4s(const float* __restrict__ p, float scale) {
    const float4 v = *(const float4*)p;
    f32x4 r = {v.x * scale, v.y * scale, v.z * scale, v.w * scale};
    return r;
}

__global__ __launch_bounds__(768)
void grugan_kernel(const float* __restrict__ noise,
                   const float* __restrict__ Wihf, const float* __restrict__ Whhf,
                   const float* __restrict__ bihf, const float* __restrict__ bhhf,
                   const float* __restrict__ Wihb, const float* __restrict__ Whhb,
                   const float* __restrict__ bihb, const float* __restrict__ bhhb,
                   const float* __restrict__ Wlat, const float* __restrict__ blat,
                   const float* __restrict__ Wout, const float* __restrict__ bout,
                   float* __restrict__ out)
{
    __shared__ __align__(16) short Xs[2][MROW][LDH];
    __shared__ __align__(16) short X2s[2][MROW][LDH];
    __shared__ __align__(16) short Hs[2][2][MROW][LDH];

    const int tid  = threadIdx.x;
    const int wave = tid >> 6;
    const int lane = tid & 63;
    const int n    = lane & 15;   // batch row within tile
    const int quad = lane >> 4;
    const int row0 = blockIdx.x * MROW;

    // zero x(0); init h(0) (gate waves hold hreg; both dirs covered)
    for (int idx = tid; idx < MROW * LDH; idx += 768) (&Xs[0][0][0])[idx] = 0;
    f32x4 hreg = {0.f, 0.f, 0.f, 0.f};
    const int gdir = wave >> 2;             // valid for waves 0-7
    const int gjq  = (wave & 3) * 16 + quad * 4;
    if (wave < 8) {
        const float4 nz = *(const float4*)&noise[(size_t)(row0 + n) * NH + gjq];
        hreg[0] = nz.x; hreg[1] = nz.y; hreg[2] = nz.z; hreg[3] = nz.w;
        *(int2*)&Hs[0][gdir][n][gjq] = pk4bf(hreg);
    }
    __syncthreads();

    if (wave < 8) {
        // ======================= GATE WAVES =======================
        const int dir  = gdir;
        const int cb   = wave & 3;
        const int jrow = cb * 16 + n;
        const int jq   = gjq;
        const float* Wih = dir ? Wihb : Wihf;
        const float* Whh = dir ? Whhb : Whhf;
        const float* bih = dir ? bihb : bihf;
        const float* bhh = dir ? bhhb : bhhf;

        // r/z rows scaled by -log2e; n rows by -2log2e (scale folding)
        s16x8 wir0 = bfragW(Wih, NH,   0 + jrow, 0, quad, NLOG2E);
        s16x8 wir1 = bfragW(Wih, NH,   0 + jrow, 1, quad, NLOG2E);
        s16x8 wiz0 = bfragW(Wih, NH,  64 + jrow, 0, quad, NLOG2E);
        s16x8 wiz1 = bfragW(Wih, NH,  64 + jrow, 1, quad, NLOG2E);
        s16x8 win0 = bfragW(Wih, NH, 128 + jrow, 0, quad, N2LOG2E);
        s16x8 win1 = bfragW(Wih, NH, 128 + jrow, 1, quad, N2LOG2E);
        s16x8 whr0 = bfragW(Whh, NH,   0 + jrow, 0, quad, NLOG2E);
        s16x8 whr1 = bfragW(Whh, NH,   0 + jrow, 1, quad, NLOG2E);
        s16x8 whz0 = bfragW(Whh, NH,  64 + jrow, 0, quad, NLOG2E);
        s16x8 whz1 = bfragW(Whh, NH,  64 + jrow, 1, quad, NLOG2E);
        s16x8 whn0 = bfragW(Whh, NH, 128 + jrow, 0, quad, N2LOG2E);
        s16x8 whn1 = bfragW(Whh, NH, 128 + jrow, 1, quad, N2LOG2E);
        f32x4 initR, initZ;
        {
            f32x4 a = bias4s(&bih[jq], NLOG2E), b = bias4s(&bhh[jq], NLOG2E);
            initR = a + b;
            f32x4 c = bias4s(&bih[64 + jq], NLOG2E), d = bias4s(&bhh[64 + jq], NLOG2E);
            initZ = c + d;
        }
        const f32x4 initN1 = bias4s(&bih[128 + jq], N2LOG2E);
        const f32x4 initN2 = bias4s(&bhh[128 + jq], N2LOG2E);

        // prologue: gh accumulators for t=0 from h(0)
        f32x4 accR, accZ, accN2;
        {
            s16x8 ha0 = *(const s16x8*)&Hs[0][dir][n][quad * 8];
            s16x8 ha1 = *(const s16x8*)&Hs[0][dir][n][32 + quad * 8];
            accR  = MFMA(whr0, ha0, initR);  accR  = MFMA(whr1, ha1, accR);
            accZ  = MFMA(whz0, ha0, initZ);  accZ  = MFMA(whz1, ha1, accZ);
            accN2 = MFMA(whn0, ha0, initN2); accN2 = MFMA(whn1, ha1, accN2);
        }

#define GSTEP(HB) do {                                                          \
        __builtin_amdgcn_s_setprio(1);  /* leg1: gates are the straggler */     \
        s16x8 xa0 = *(const s16x8*)&Xs[HB][n][quad * 8];                        \
        s16x8 xa1 = *(const s16x8*)&Xs[HB][n][32 + quad * 8];                   \
        accR = MFMA(wir0, xa0, accR);   accR = MFMA(wir1, xa1, accR);           \
        accZ = MFMA(wiz0, xa0, accZ);   accZ = MFMA(wiz1, xa1, accZ);           \
        f32x4 accN1 = MFMA(win0, xa0, initN1);                                  \
        accN1 = MFMA(win1, xa1, accN1);                                         \
        /* scale-folded: accR/accZ = -log2e*(gi+gh), accN* = -2log2e*(...) */   \
        f32x4 eR = v_exp2(accR);                                                \
        f32x4 rr = v_rcp(eR + 1.0f);                                            \
        f32x4 eU = v_exp2(accN1 + rr * accN2);                                  \
        f32x4 eZ = v_exp2(accZ);                                                \
        f32x4 numer = (eZ + hreg) + eU * (hreg - eZ);                           \
        f32x4 denom = (eU + 1.0f) * (eZ + 1.0f);                                \
        hreg = numer * v_rcp(denom);                                            \
        *(int2*)&Hs[(HB) ^ 1][dir][n][jq] = pk4bf(hreg);                        \
        __builtin_amdgcn_s_setprio(0);  /* leg2: yield to latent waves */       \
        __syncthreads();  /* b1: H(t+1) visible */                              \
        {                                                                       \
            s16x8 ha0 = *(const s16x8*)&Hs[(HB) ^ 1][dir][n][quad * 8];         \
            s16x8 ha1 = *(const s16x8*)&Hs[(HB) ^ 1][dir][n][32 + quad * 8];    \
            accR  = MFMA(whr0, ha0, initR);  accR  = MFMA(whr1, ha1, accR);     \
            accZ  = MFMA(whz0, ha0, initZ);  accZ  = MFMA(whz1, ha1, accZ);     \
            accN2 = MFMA(whn0, ha0, initN2); accN2 = MFMA(whn1, ha1, accN2);    \
        }                                                                       \
        __syncthreads();  /* b2: x(t+1) visible */                              \
    } while (0)

        for (int t = 0; t < NS; t += 2) {
            GSTEP(0);
            GSTEP(1);
        }
#undef GSTEP
    } else {
        // =============== LATENT WAVES (+ fused OUT-PROJ on lt<2) ===============
        const int lt = wave & 3;
        const int nq = lt * 16 + quad * 4;
        s16x8 wl0 = bfragW(Wlat, 2 * NH, lt * 16 + n, 0, quad, 1.0f);
        s16x8 wl1 = bfragW(Wlat, 2 * NH, lt * 16 + n, 1, quad, 1.0f);
        s16x8 wl2 = bfragW(Wlat, 2 * NH, lt * 16 + n, 2, quad, 1.0f);
        s16x8 wl3 = bfragW(Wlat, 2 * NH, lt * 16 + n, 3, quad, 1.0f);
        const f32x4 initL = bias4s(&blat[lt * 16 + quad * 4], 1.0f);

        // out-proj state (waves 8-9 only: f-tile f0 = lt*16), pre-scaled -log2e
        s16x8 wo0 = {};
        s16x8 wo1 = {};
        f32x4 initO = {0.f, 0.f, 0.f, 0.f};
        float* orow = nullptr;
        if (lt < 2) {
            const int f0 = lt * 16;
            wo0   = bfragW(Wout, NH, f0 + n, 0, quad, NLOG2E);
            wo1   = bfragW(Wout, NH, f0 + n, 1, quad, NLOG2E);
            initO = bias4s(&bout[f0 + quad * 4], NLOG2E);
            orow  = out + (size_t)(row0 + n) * (NS * NF) + f0 + quad * 4;
        }
        const f32x4 zero4 = {0.f, 0.f, 0.f, 0.f};

#define LOSTEP(HB, T) do {                                                      \
        if (lt < 2 && (T) > 0) {                                                \
            /* leg1 (prio 0 — slack): out-proj of y(T-1) from X2s[HB];  */      \
            /* store never drained (raw barriers keep vmcnt outstanding). */    \
            s16x8 p0 = *(const s16x8*)&X2s[HB][n][quad * 8];                    \
            s16x8 p1 = *(const s16x8*)&X2s[HB][n][32 + quad * 8];               \
            f32x4 po = MFMA(wo0, p0, initO);                                    \
            po = MFMA(wo1, p1, po);                                             \
            *(f32x4*)(orow + (size_t)((T) - 1) * NF) = v_sigm_pre(po);          \
        }                                                                       \
        bar_nodrain();    /* b1: H(T+1) visible (we have nothing pending) */    \
        __builtin_amdgcn_s_setprio(1);  /* leg2: latent is the straggler */     \
        s16x8 fa0 = *(const s16x8*)&Hs[(HB) ^ 1][0][n][quad * 8];               \
        s16x8 fa1 = *(const s16x8*)&Hs[(HB) ^ 1][0][n][32 + quad * 8];          \
        s16x8 ba0 = *(const s16x8*)&Hs[(HB) ^ 1][1][n][quad * 8];               \
        s16x8 ba1 = *(const s16x8*)&Hs[(HB) ^ 1][1][n][32 + quad * 8];          \
        f32x4 lac1 = MFMA(wl0, fa0, initL);                                     \
        lac1 = MFMA(wl1, fa1, lac1);                                            \
        f32x4 lac2 = MFMA(wl2, ba0, zero4);                                     \
        lac2 = MFMA(wl3, ba1, lac2);                                            \
        f32x4 la = lac1 + lac2;                                                 \
        *(int2*)&Xs[(HB) ^ 1][n][nq]  = pk4bf(v_lk(la));                        \
        *(int2*)&X2s[(HB) ^ 1][n][nq] = pk4bf(v_lk2(la));                       \
        __builtin_amdgcn_s_setprio(0);  /* leg1: yield to gate waves */         \
        bar_lgkm();       /* b2: x(T+1) visible (lgkm drain only) */            \
    } while (0)

        for (int t = 0; t < NS; t += 2) {
            LOSTEP(0, t);
            LOSTEP(1, t + 1);
        }
#undef LOSTEP

        // epilogue: y(NS-1) from X2s[0] (= lk2(x(NS)), written at T=NS-1,
        // visible via the loop's final bar_lgkm)
        if (lt < 2) {
            s16x8 p0 = *(const s16x8*)&X2s[0][n][quad * 8];
            s16x8 p1 = *(const s16x8*)&X2s[0][n][32 + quad * 8];
            f32x4 po = MFMA(wo0, p0, initO);
            po = MFMA(wo1, p1, po);
            *(f32x4*)(orow + (size_t)(NS - 1) * NF) = v_sigm_pre(po);
        }
    }
}

extern "C" void kernel_launch(void* const* d_in, const int* in_sizes, int n_in,
                              void* d_out, int out_size, void* d_ws, size_t ws_size,
                              hipStream_t stream) {
    const float* noise = (const float*)d_in[0];
    const float* Wihf  = (const float*)d_in[1];
    const float* Whhf  = (const float*)d_in[2];
    const float* bihf  = (const float*)d_in[3];
    const float* bhhf  = (const float*)d_in[4];
    const float* Wihb  = (const float*)d_in[5];
    const float* Whhb  = (const float*)d_in[6];
    const float* bihb  = (const float*)d_in[7];
    const float* bhhb  = (const float*)d_in[8];
    const float* Wlat  = (const float*)d_in[9];
    const float* blat  = (const float*)d_in[10];
    const float* Wout  = (const float*)d_in[11];
    const float* bout  = (const float*)d_in[12];

    grugan_kernel<<<dim3(NBATCH / MROW), dim3(768), 0, stream>>>(
        noise, Wihf, Whhf, bihf, bhhf, Wihb, Whhb, bihb, bhhb,
        Wlat, blat, Wout, bout, (float*)d_out);
}